// Round 8
// baseline (163.954 us; speedup 1.0000x reference)
//
#include <hip/hip_runtime.h>
#include <hip/hip_bf16.h>

#define NN   100000   // nodes
#define EE   500000   // edges
#define MPAD 100096   // 782 * 128

using bf16x8 = __attribute__((ext_vector_type(8))) short;
using f32x4  = __attribute__((ext_vector_type(4))) float;
using u16x8  = __attribute__((ext_vector_type(8))) unsigned short;

__device__ __forceinline__ unsigned short f2bf(float f) {
  unsigned int x = __builtin_bit_cast(unsigned int, f);
  x += 0x7fffu + ((x >> 16) & 1u);           // round-to-nearest-even
  return (unsigned short)(x >> 16);
}
__device__ __forceinline__ float bf2f(unsigned short u) {
  unsigned int x = ((unsigned int)u) << 16;
  return __builtin_bit_cast(float, x);
}
// HW RNE cvt (compiler emits v_cvt_pk_bf16_f32 for pairs)
__device__ __forceinline__ unsigned short f2bh(float f) {
  return __builtin_bit_cast(unsigned short, __float2bfloat16(f));
}
__device__ __forceinline__ void glds16(const void* g, const void* l) {
  __builtin_amdgcn_global_load_lds((const __attribute__((address_space(1))) void*)g,
                                   (__attribute__((address_space(3))) void*)l, 16, 0, 0);
}

// ---------------- Pass 1: WT[j][k] = bf16(W1[k + 256*(j>=256)][j&255]) ----------------
__global__ void wprep_kernel(const float* __restrict__ W1, unsigned short* __restrict__ WT) {
  int id = blockIdx.x * blockDim.x + threadIdx.x;
  if (id >= 512 * 32) return;
  int j  = id >> 5;        // 0..511
  int cg = id & 31;        // 8-element k-chunk
  int jc = j & 255;
  int kb = (cg << 3) + ((j >= 256) ? 256 : 0);
  u16x8 v;
#pragma unroll
  for (int t = 0; t < 8; ++t)
    v[t] = f2bf(W1[(size_t)(kb + t) * 256 + jc]);
  *reinterpret_cast<u16x8*>(WT + (size_t)j * 256 + (cg << 3)) = v;
}

// ---------------- Pass 2: R[MPAD][512] bf16 = emb @ WT^T (+ b1 on src half) ----------------
// R5 structure with 100% DMA staging: A staged as RAW FP32 via global_load_lds (no cvt, no
// reg round-trip, no ds_write), B staged bf16 via global_load_lds. fp32->bf16 conversion
// happens at fragment-read time (cvt_pk, dependency-light). Chunk-XOR swizzle on both
// (pre-swizzled glds sources; <=2-way conflicts = free). 128x128 tile, BK=32, dbuf,
// one barrier per K-step, XCD-bijective block swizzle, b1 folded in epilogue.
__global__ __launch_bounds__(256, 3) void gemm_pq(const float* __restrict__ emb,
                                                  const unsigned short* __restrict__ WT,
                                                  const float* __restrict__ b1,
                                                  unsigned short* __restrict__ R) {
  __shared__ float          ldsA[2][128 * 32];   // fp32, chunk-swizzled (32 KB)
  __shared__ unsigned short ldsB[2][128 * 32];   // bf16, chunk-swizzled (16 KB)

  const int t    = threadIdx.x;
  const int lane = t & 63;
  const int wave = t >> 6;
  const int wrow = wave >> 1, wcol = wave & 1;
  // XCD-bijective swizzle (3128 = 8*391); 4 n-siblings of an m-tile share an XCD L2.
  const int bid = (int)blockIdx.x;
  const int lid = (bid & 7) * 391 + (bid >> 3);
  const int m0 = (lid >> 2) * 128;
  const int n0 = (lid & 3) * 128;

  // ---- A glds: 4 instrs/wave/K-step, 1 KB each. Lane -> row = w*32+i*8+(l>>3),
  //      slot s=(l&7)>>1, half h=l&1. Slot s of row r holds global chunk s^((r>>1)&3).
  size_t aOff[4]; int aLds[4];
#pragma unroll
  for (int i = 0; i < 4; ++i) {
    const int row = wave * 32 + i * 8 + (lane >> 3);
    const int s   = (lane & 7) >> 1, h = lane & 1;
    const int g   = s ^ ((row >> 1) & 3);
    int rowg = m0 + row; if (rowg >= NN) rowg = NN - 1;     // clamp; pad rows unused
    aOff[i] = (size_t)rowg * 256 + (g << 3) + (h << 2);
    aLds[i] = wave * 1024 + i * 256;                        // fp32 elems, wave-uniform
  }
  // ---- B glds: 2 instrs/wave/K-step. Lane -> row = w*32+i*16+(l>>2), slot qp=l&3.
  size_t bOff[2]; int bLds[2];
#pragma unroll
  for (int i = 0; i < 2; ++i) {
    const int r  = wave * 32 + i * 16 + (lane >> 2);
    const int qp = lane & 3;
    const int g  = qp ^ ((r >> 1) & 3);
    bOff[i] = (size_t)(n0 + r) * 256 + (g << 3);
    bLds[i] = (wave * 32 + i * 16) * 32;                    // bf16 elems, wave-uniform
  }

  // ---- fragment addressing (elems; slot = fq ^ ((r>>1)&3), proven 0-conflict)
  const int fr = lane & 15, fq = lane >> 4;
  int aoff[4], boff[4];
#pragma unroll
  for (int m = 0; m < 4; ++m) {
    const int r = wrow * 64 + 16 * m + fr;
    aoff[m] = r * 32 + ((fq ^ ((r >> 1) & 3)) << 3);
  }
#pragma unroll
  for (int n = 0; n < 4; ++n) {
    const int r = wcol * 64 + 16 * n + fr;
    boff[n] = r * 32 + ((fq ^ ((r >> 1) & 3)) << 3);
  }

#define STAGE(buf, ks)                                                         \
  do {                                                                         \
    glds16(emb + aOff[0] + ((ks) << 5), &ldsA[(buf)][aLds[0]]);                \
    glds16(emb + aOff[1] + ((ks) << 5), &ldsA[(buf)][aLds[1]]);                \
    glds16(emb + aOff[2] + ((ks) << 5), &ldsA[(buf)][aLds[2]]);                \
    glds16(emb + aOff[3] + ((ks) << 5), &ldsA[(buf)][aLds[3]]);                \
    glds16(WT + bOff[0] + ((ks) << 5), &ldsB[(buf)][bLds[0]]);                 \
    glds16(WT + bOff[1] + ((ks) << 5), &ldsB[(buf)][bLds[1]]);                 \
  } while (0)

  f32x4 acc[4][4] = {};

  STAGE(0, 0);
  __syncthreads();

#pragma unroll
  for (int ks = 0; ks < 8; ++ks) {
    const int p = ks & 1;
    if (ks < 7) STAGE(p ^ 1, ks + 1);            // DMA next tile; flies across compute
    bf16x8 av[4], bv[4];
#pragma unroll
    for (int m = 0; m < 4; ++m) {                // fp32 frag -> cvt -> bf16x8
      const float* pa = &ldsA[p][aoff[m]];
      float4 x0 = *(const float4*)pa;
      float4 x1 = *(const float4*)(pa + 4);
      bf16x8 a;
      a[0] = (short)f2bh(x0.x); a[1] = (short)f2bh(x0.y);
      a[2] = (short)f2bh(x0.z); a[3] = (short)f2bh(x0.w);
      a[4] = (short)f2bh(x1.x); a[5] = (short)f2bh(x1.y);
      a[6] = (short)f2bh(x1.z); a[7] = (short)f2bh(x1.w);
      av[m] = a;
    }
#pragma unroll
    for (int n = 0; n < 4; ++n) bv[n] = *(const bf16x8*)&ldsB[p][boff[n]];
#pragma unroll
    for (int m = 0; m < 4; ++m)
#pragma unroll
      for (int n = 0; n < 4; ++n)
        acc[m][n] = __builtin_amdgcn_mfma_f32_16x16x32_bf16(av[m], bv[n], acc[m][n], 0, 0, 0);
    __syncthreads();                             // drains next-tile glds + frag reads
  }

  // epilogue: col = lane&15 (+16n), row = (lane>>4)*4 + i; m-outer/n-inner (full 128B lines)
  float bn[4];
#pragma unroll
  for (int n = 0; n < 4; ++n) {
    const int c = n0 + wcol * 64 + 16 * n + fr;
    bn[n] = (c < 256) ? b1[c] : 0.f;
  }
#pragma unroll
  for (int m = 0; m < 4; ++m) {
    const int r0 = m0 + wrow * 64 + 16 * m + (fq << 2);
#pragma unroll
    for (int n = 0; n < 4; ++n) {
      const int c = n0 + wcol * 64 + 16 * n + fr;
#pragma unroll
      for (int i = 0; i < 4; ++i)
        R[(size_t)(r0 + i) * 512 + c] = f2bh(acc[m][n][i] + bn[n]);
    }
  }
#undef STAGE
}

// ---------------- Pass 3: 8 edges per wave-iteration, 2 edges in flight via lane split ----
// score[e] = b2 + sum_j relu(R[src][j] + R[dst][256+j]) * W2[j]   (b1 pre-folded into R)
__global__ __launch_bounds__(256) void edge_kernel(const int* __restrict__ idx,
                                                   const unsigned short* __restrict__ R,
                                                   const float* __restrict__ W2,
                                                   const float* __restrict__ b2,
                                                   float* __restrict__ out) {
  const int lane  = threadIdx.x & 63;
  const int half  = lane >> 5;         // which of the 2 concurrent edges this lane serves
  const int l     = lane & 31;         // 32 lanes x 8 channels = 256 channels
  const int gwave = (int)((blockIdx.x * blockDim.x + threadIdx.x) >> 6);
  const int nwave = (int)((gridDim.x * blockDim.x) >> 6);
  const float4 w0 = *(const float4*)(W2 + (l << 3));
  const float4 w1 = *(const float4*)(W2 + (l << 3) + 4);
  const float bias = b2[0];

  for (int c = gwave; c < (EE / 8); c += nwave) {
    const int e0 = c << 3;
    int s[4], d[4];
#pragma unroll
    for (int u = 0; u < 4; ++u) {                // edge for this lane: e0 + 2u + half
      s[u] = idx[e0 + (u << 1) + half];
      d[u] = idx[EE + e0 + (u << 1) + half];
    }
    u16x8 ga[4], gb[4];
#pragma unroll
    for (int u = 0; u < 4; ++u) {                // issue all 16 gathers before reducing
      ga[u] = *(const u16x8*)(R + (size_t)s[u] * 512 + (l << 3));
      gb[u] = *(const u16x8*)(R + (size_t)d[u] * 512 + 256 + (l << 3));
    }
#pragma unroll
    for (int u = 0; u < 4; ++u) {
      float acc;
      acc  = fmaxf(bf2f((unsigned short)ga[u][0]) + bf2f((unsigned short)gb[u][0]), 0.f) * w0.x;
      acc += fmaxf(bf2f((unsigned short)ga[u][1]) + bf2f((unsigned short)gb[u][1]), 0.f) * w0.y;
      acc += fmaxf(bf2f((unsigned short)ga[u][2]) + bf2f((unsigned short)gb[u][2]), 0.f) * w0.z;
      acc += fmaxf(bf2f((unsigned short)ga[u][3]) + bf2f((unsigned short)gb[u][3]), 0.f) * w0.w;
      acc += fmaxf(bf2f((unsigned short)ga[u][4]) + bf2f((unsigned short)gb[u][4]), 0.f) * w1.x;
      acc += fmaxf(bf2f((unsigned short)ga[u][5]) + bf2f((unsigned short)gb[u][5]), 0.f) * w1.y;
      acc += fmaxf(bf2f((unsigned short)ga[u][6]) + bf2f((unsigned short)gb[u][6]), 0.f) * w1.z;
      acc += fmaxf(bf2f((unsigned short)ga[u][7]) + bf2f((unsigned short)gb[u][7]), 0.f) * w1.w;
#pragma unroll
      for (int off = 16; off > 0; off >>= 1) acc += __shfl_xor(acc, off, 64);
      if (l == 0) out[e0 + (u << 1) + half] = acc + bias;
    }
  }
}

// ---------------- Fallback (only if ws is too small): direct, slow, correct ----------------
__global__ __launch_bounds__(256) void fallback_kernel(const float* __restrict__ emb,
                                                       const int* __restrict__ idx,
                                                       const float* __restrict__ W1,
                                                       const float* __restrict__ b1,
                                                       const float* __restrict__ W2,
                                                       const float* __restrict__ b2,
                                                       float* __restrict__ out) {
  __shared__ float feats[512];
  __shared__ float red[256];
  const int t = threadIdx.x;
  for (int e = blockIdx.x; e < EE; e += gridDim.x) {
    __syncthreads();
    const int s = idx[e], d = idx[EE + e];
    feats[t]       = emb[(size_t)s * 256 + t];
    feats[256 + t] = emb[(size_t)d * 256 + t];
    __syncthreads();
    float h = b1[t];
    for (int k = 0; k < 512; ++k) h += feats[k] * W1[k * 256 + t];
    red[t] = fmaxf(h, 0.f) * W2[t];
    __syncthreads();
    for (int off = 128; off > 0; off >>= 1) {
      if (t < off) red[t] += red[t + off];
      __syncthreads();
    }
    if (t == 0) out[e] = red[0] + b2[0];
  }
}

extern "C" void kernel_launch(void* const* d_in, const int* in_sizes, int n_in,
                              void* d_out, int out_size, void* d_ws, size_t ws_size,
                              hipStream_t stream) {
  const float* emb = (const float*)d_in[0];
  const int*   idx = (const int*)d_in[1];
  const float* W1  = (const float*)d_in[2];
  const float* b1  = (const float*)d_in[3];
  const float* W2  = (const float*)d_in[4];
  const float* b2  = (const float*)d_in[5];
  float* out = (float*)d_out;

  const size_t wt_elems = (size_t)512 * 256;
  const size_t r_elems  = (size_t)MPAD * 512;
  const size_t need = (wt_elems + r_elems) * sizeof(unsigned short);

  if (ws_size < need) {
    fallback_kernel<<<4096, 256, 0, stream>>>(emb, idx, W1, b1, W2, b2, out);
    return;
  }

  unsigned short* WT = (unsigned short*)d_ws;
  unsigned short* R  = WT + wt_elems;

  wprep_kernel<<<64, 256, 0, stream>>>(W1, WT);
  gemm_pq<<<(MPAD / 128) * 4, 256, 0, stream>>>(emb, WT, b1, R);
  edge_kernel<<<2048, 256, 0, stream>>>(idx, R, W2, b2, out);
}

// Round 9
// 136.802 us; speedup vs baseline: 1.1985x; 1.1985x over previous
//
#include <hip/hip_runtime.h>
#include <hip/hip_bf16.h>

#define NN   100000   // nodes
#define EE   500000   // edges
#define MPAD 100096   // 782 * 128

using bf16x8 = __attribute__((ext_vector_type(8))) short;
using f32x4  = __attribute__((ext_vector_type(4))) float;
using u16x8  = __attribute__((ext_vector_type(8))) unsigned short;

__device__ __forceinline__ unsigned short f2bf(float f) {
  unsigned int x = __builtin_bit_cast(unsigned int, f);
  x += 0x7fffu + ((x >> 16) & 1u);           // round-to-nearest-even
  return (unsigned short)(x >> 16);
}
__device__ __forceinline__ float bf2f(unsigned short u) {
  unsigned int x = ((unsigned int)u) << 16;
  return __builtin_bit_cast(float, x);
}
// HW RNE cvt (compiler emits v_cvt_pk_bf16_f32 for pairs)
__device__ __forceinline__ unsigned short f2bh(float f) {
  return __builtin_bit_cast(unsigned short, __float2bfloat16(f));
}
__device__ __forceinline__ void glds16(const void* g, const void* l) {
  __builtin_amdgcn_global_load_lds((const __attribute__((address_space(1))) void*)g,
                                   (__attribute__((address_space(3))) void*)l, 16, 0, 0);
}

// ---------------- Pass 1: WT[j][k] = bf16(W1[k + 256*(j>=256)][j&255]) ----------------
__global__ void wprep_kernel(const float* __restrict__ W1, unsigned short* __restrict__ WT) {
  int id = blockIdx.x * blockDim.x + threadIdx.x;
  if (id >= 512 * 32) return;
  int j  = id >> 5;        // 0..511
  int cg = id & 31;        // 8-element k-chunk
  int jc = j & 255;
  int kb = (cg << 3) + ((j >= 256) ? 256 : 0);
  u16x8 v;
#pragma unroll
  for (int t = 0; t < 8; ++t)
    v[t] = f2bf(W1[(size_t)(kb + t) * 256 + jc]);
  *reinterpret_cast<u16x8*>(WT + (size_t)j * 256 + (cg << 3)) = v;
}

// ---------------- Pass 2: R[MPAD][512] bf16 = emb @ WT^T (+ b1 on src half) ----------------
// R5 addressing (proven numerically + 0 bank conflicts) with a counted-vmcnt pipeline:
// triple-buffered LDS for A (bf16, reg-staged, 2 register stages -> ~2 K-steps of HBM
// flight) and B (glds DMA). One raw s_barrier per K-step, s_waitcnt vmcnt(N) with exact
// counts {10,10,10,10,10,6,2,0} - NEVER a vmcnt(0) drain in steady state (T3/T4).
__global__ __launch_bounds__(256, 3) void gemm_pq(const float* __restrict__ emb,
                                                  const unsigned short* __restrict__ WT,
                                                  const float* __restrict__ b1,
                                                  unsigned short* __restrict__ R) {
  __shared__ unsigned short ldsA[3][128 * 32];   // 8 KB each
  __shared__ unsigned short ldsB[3][128 * 32];   // 8 KB each

  const int t    = threadIdx.x;
  const int lane = t & 63;
  const int wave = t >> 6;
  const int wrow = wave >> 1, wcol = wave & 1;
  // XCD-bijective swizzle (3128 = 8*391)
  const int bid = (int)blockIdx.x;
  const int lid = (bid & 7) * 391 + (bid >> 3);
  const int m0 = (lid >> 2) * 128;
  const int n0 = (lid & 3) * 128;

  // ---- A staging (reg): thread -> row a_r = t>>1, half a_h = t&1 (16 fp32 per slice)
  const int a_r = t >> 1, a_h = t & 1;
  int arow_g = m0 + a_r; if (arow_g >= NN) arow_g = NN - 1;   // clamp; pad rows unused
  const float* aSrc = emb + (size_t)arow_g * 256 + (a_h << 4);
  const int a_s  = (a_r >> 1) & 3;
  const int aW0  = a_r * 32 + ((((a_h << 1) | 0) ^ a_s) << 3);
  const int aW1  = a_r * 32 + ((((a_h << 1) | 1) ^ a_s) << 3);

  // ---- B staging (glds): 2 instrs/wave/K-step; lane -> row = w*32+i*16+(l>>2), slot qp=l&3
  size_t bOff[2]; int bLds[2];
#pragma unroll
  for (int i = 0; i < 2; ++i) {
    const int r  = wave * 32 + i * 16 + (lane >> 2);
    const int qp = lane & 3;
    const int g  = qp ^ ((r >> 1) & 3);              // pre-swizzled global chunk
    bOff[i] = (size_t)(n0 + r) * 256 + (g << 3);
    bLds[i] = (wave * 32 + i * 16) * 32;             // wave-uniform base (elems)
  }

  // ---- fragment read offsets (proven 0-conflict)
  const int fr = lane & 15, fq = lane >> 4;
  int aoff[4], boff[4];
#pragma unroll
  for (int m = 0; m < 4; ++m) {
    const int r = wrow * 64 + 16 * m + fr;
    aoff[m] = r * 32 + ((fq ^ ((r >> 1) & 3)) << 3);
  }
#pragma unroll
  for (int n = 0; n < 4; ++n) {
    const int r = wcol * 64 + 16 * n + fr;
    boff[n] = r * 32 + ((fq ^ ((r >> 1) & 3)) << 3);
  }

  f32x4 acc[4][4] = {};
  float4 pX[4], pY[4];

#define ALOAD(reg, slice)                                                      \
  do {                                                                         \
    reg[0] = *(const float4*)(aSrc + ((slice) << 5));                          \
    reg[1] = *(const float4*)(aSrc + ((slice) << 5) + 4);                      \
    reg[2] = *(const float4*)(aSrc + ((slice) << 5) + 8);                      \
    reg[3] = *(const float4*)(aSrc + ((slice) << 5) + 12);                     \
  } while (0)

#define AWRITE(buf, reg)                                                       \
  do {                                                                         \
    u16x8 w0, w1;                                                              \
    w0[0] = f2bh(reg[0].x); w0[1] = f2bh(reg[0].y);                            \
    w0[2] = f2bh(reg[0].z); w0[3] = f2bh(reg[0].w);                            \
    w0[4] = f2bh(reg[1].x); w0[5] = f2bh(reg[1].y);                            \
    w0[6] = f2bh(reg[1].z); w0[7] = f2bh(reg[1].w);                            \
    w1[0] = f2bh(reg[2].x); w1[1] = f2bh(reg[2].y);                            \
    w1[2] = f2bh(reg[2].z); w1[3] = f2bh(reg[2].w);                            \
    w1[4] = f2bh(reg[3].x); w1[5] = f2bh(reg[3].y);                            \
    w1[6] = f2bh(reg[3].z); w1[7] = f2bh(reg[3].w);                            \
    *(u16x8*)&ldsA[(buf)][aW0] = w0;                                           \
    *(u16x8*)&ldsA[(buf)][aW1] = w1;                                           \
  } while (0)

#define BGLDS(buf, slice)                                                      \
  do {                                                                         \
    glds16(WT + bOff[0] + ((slice) << 5), &ldsB[(buf)][bLds[0]]);              \
    glds16(WT + bOff[1] + ((slice) << 5), &ldsB[(buf)][bLds[1]]);              \
  } while (0)

#define COMPUTE(p)                                                             \
  do {                                                                         \
    bf16x8 av[4], bv[4];                                                       \
    _Pragma("unroll")                                                          \
    for (int m = 0; m < 4; ++m) av[m] = *(const bf16x8*)&ldsA[(p)][aoff[m]];   \
    _Pragma("unroll")                                                          \
    for (int n = 0; n < 4; ++n) bv[n] = *(const bf16x8*)&ldsB[(p)][boff[n]];   \
    _Pragma("unroll")                                                          \
    for (int m = 0; m < 4; ++m)                                                \
      _Pragma("unroll")                                                        \
      for (int n = 0; n < 4; ++n)                                              \
        acc[m][n] = __builtin_amdgcn_mfma_f32_16x16x32_bf16(av[m], bv[n],      \
                                                            acc[m][n], 0, 0, 0); \
  } while (0)

#define SB() __builtin_amdgcn_sched_barrier(0)

  // STEP ks: write slice ks+1 (loaded 2 steps ago), stage B slice ks+1, load A slice ks+3,
  // then counted wait + barrier, compute slice ks. NW = exact newer-ops count so the wait
  // releases as soon as B(ks) [and transitively A(ks+2)] are done.
#define STEP(ks, preg, NW)                                                     \
  do {                                                                         \
    if ((ks) < 7) { AWRITE((ks + 1) % 3, preg); }                              \
    SB();                                                                      \
    if ((ks) < 7) { BGLDS((ks + 1) % 3, (ks) + 1); }                           \
    SB();                                                                      \
    if ((ks) <= 4) { ALOAD(preg, (ks) + 3); }                                  \
    SB();                                                                      \
    asm volatile("s_waitcnt vmcnt(" #NW ") lgkmcnt(0)" ::: "memory");          \
    __builtin_amdgcn_s_barrier();                                              \
    SB();                                                                      \
    COMPUTE((ks) % 3);                                                         \
  } while (0)

  // prologue: A(0)->pX, A(1)->pY, write slice0, B(0), A(2)->pX, wait B(0), barrier
  ALOAD(pX, 0); SB();
  ALOAD(pY, 1); SB();
  AWRITE(0, pX); SB();
  BGLDS(0, 0); SB();
  ALOAD(pX, 2); SB();
  asm volatile("s_waitcnt vmcnt(4) lgkmcnt(0)" ::: "memory");
  __builtin_amdgcn_s_barrier();
  SB();

  STEP(0, pY, 10);
  STEP(1, pX, 10);
  STEP(2, pY, 10);
  STEP(3, pX, 10);
  STEP(4, pY, 10);
  STEP(5, pX, 6);
  STEP(6, pY, 2);
  STEP(7, pX, 0);

  // epilogue: col = lane&15 (+16n), row = (lane>>4)*4 + i; m-outer/n-inner (full 128B lines)
  float bn[4];
#pragma unroll
  for (int n = 0; n < 4; ++n) {
    const int c = n0 + wcol * 64 + 16 * n + fr;
    bn[n] = (c < 256) ? b1[c] : 0.f;
  }
#pragma unroll
  for (int m = 0; m < 4; ++m) {
    const int r0 = m0 + wrow * 64 + 16 * m + (fq << 2);
#pragma unroll
    for (int n = 0; n < 4; ++n) {
      const int c = n0 + wcol * 64 + 16 * n + fr;
#pragma unroll
      for (int i = 0; i < 4; ++i)
        R[(size_t)(r0 + i) * 512 + c] = f2bh(acc[m][n][i] + bn[n]);
    }
  }
#undef ALOAD
#undef AWRITE
#undef BGLDS
#undef COMPUTE
#undef STEP
#undef SB
}

// ---------------- Pass 3: 8 edges per wave-iteration, 2 edges in flight via lane split ----
// score[e] = b2 + sum_j relu(R[src][j] + R[dst][256+j]) * W2[j]   (b1 pre-folded into R)
__global__ __launch_bounds__(256) void edge_kernel(const int* __restrict__ idx,
                                                   const unsigned short* __restrict__ R,
                                                   const float* __restrict__ W2,
                                                   const float* __restrict__ b2,
                                                   float* __restrict__ out) {
  const int lane  = threadIdx.x & 63;
  const int half  = lane >> 5;         // which of the 2 concurrent edges this lane serves
  const int l     = lane & 31;         // 32 lanes x 8 channels = 256 channels
  const int gwave = (int)((blockIdx.x * blockDim.x + threadIdx.x) >> 6);
  const int nwave = (int)((gridDim.x * blockDim.x) >> 6);
  const float4 w0 = *(const float4*)(W2 + (l << 3));
  const float4 w1 = *(const float4*)(W2 + (l << 3) + 4);
  const float bias = b2[0];

  for (int c = gwave; c < (EE / 8); c += nwave) {
    const int e0 = c << 3;
    int s[4], d[4];
#pragma unroll
    for (int u = 0; u < 4; ++u) {                // edge for this lane: e0 + 2u + half
      s[u] = idx[e0 + (u << 1) + half];
      d[u] = idx[EE + e0 + (u << 1) + half];
    }
    u16x8 ga[4], gb[4];
#pragma unroll
    for (int u = 0; u < 4; ++u) {                // issue all 16 gathers before reducing
      ga[u] = *(const u16x8*)(R + (size_t)s[u] * 512 + (l << 3));
      gb[u] = *(const u16x8*)(R + (size_t)d[u] * 512 + 256 + (l << 3));
    }
#pragma unroll
    for (int u = 0; u < 4; ++u) {
      float acc;
      acc  = fmaxf(bf2f((unsigned short)ga[u][0]) + bf2f((unsigned short)gb[u][0]), 0.f) * w0.x;
      acc += fmaxf(bf2f((unsigned short)ga[u][1]) + bf2f((unsigned short)gb[u][1]), 0.f) * w0.y;
      acc += fmaxf(bf2f((unsigned short)ga[u][2]) + bf2f((unsigned short)gb[u][2]), 0.f) * w0.z;
      acc += fmaxf(bf2f((unsigned short)ga[u][3]) + bf2f((unsigned short)gb[u][3]), 0.f) * w0.w;
      acc += fmaxf(bf2f((unsigned short)ga[u][4]) + bf2f((unsigned short)gb[u][4]), 0.f) * w1.x;
      acc += fmaxf(bf2f((unsigned short)ga[u][5]) + bf2f((unsigned short)gb[u][5]), 0.f) * w1.y;
      acc += fmaxf(bf2f((unsigned short)ga[u][6]) + bf2f((unsigned short)gb[u][6]), 0.f) * w1.z;
      acc += fmaxf(bf2f((unsigned short)ga[u][7]) + bf2f((unsigned short)gb[u][7]), 0.f) * w1.w;
#pragma unroll
      for (int off = 16; off > 0; off >>= 1) acc += __shfl_xor(acc, off, 64);
      if (l == 0) out[e0 + (u << 1) + half] = acc + bias;
    }
  }
}

// ---------------- Fallback (only if ws is too small): direct, slow, correct ----------------
__global__ __launch_bounds__(256) void fallback_kernel(const float* __restrict__ emb,
                                                       const int* __restrict__ idx,
                                                       const float* __restrict__ W1,
                                                       const float* __restrict__ b1,
                                                       const float* __restrict__ W2,
                                                       const float* __restrict__ b2,
                                                       float* __restrict__ out) {
  __shared__ float feats[512];
  __shared__ float red[256];
  const int t = threadIdx.x;
  for (int e = blockIdx.x; e < EE; e += gridDim.x) {
    __syncthreads();
    const int s = idx[e], d = idx[EE + e];
    feats[t]       = emb[(size_t)s * 256 + t];
    feats[256 + t] = emb[(size_t)d * 256 + t];
    __syncthreads();
    float h = b1[t];
    for (int k = 0; k < 512; ++k) h += feats[k] * W1[k * 256 + t];
    red[t] = fmaxf(h, 0.f) * W2[t];
    __syncthreads();
    for (int off = 128; off > 0; off >>= 1) {
      if (t < off) red[t] += red[t + off];
      __syncthreads();
    }
    if (t == 0) out[e] = red[0] + b2[0];
  }
}

extern "C" void kernel_launch(void* const* d_in, const int* in_sizes, int n_in,
                              void* d_out, int out_size, void* d_ws, size_t ws_size,
                              hipStream_t stream) {
  const float* emb = (const float*)d_in[0];
  const int*   idx = (const int*)d_in[1];
  const float* W1  = (const float*)d_in[2];
  const float* b1  = (const float*)d_in[3];
  const float* W2  = (const float*)d_in[4];
  const float* b2  = (const float*)d_in[5];
  float* out = (float*)d_out;

  const size_t wt_elems = (size_t)512 * 256;
  const size_t r_elems  = (size_t)MPAD * 512;
  const size_t need = (wt_elems + r_elems) * sizeof(unsigned short);

  if (ws_size < need) {
    fallback_kernel<<<4096, 256, 0, stream>>>(emb, idx, W1, b1, W2, b2, out);
    return;
  }

  unsigned short* WT = (unsigned short*)d_ws;
  unsigned short* R  = WT + wt_elems;

  wprep_kernel<<<64, 256, 0, stream>>>(W1, WT);
  gemm_pq<<<(MPAD / 128) * 4, 256, 0, stream>>>(emb, WT, b1, R);
  edge_kernel<<<2048, 256, 0, stream>>>(idx, R, W2, b2, out);
}